// Round 7
// baseline (98.947 us; speedup 1.0000x reference)
//
#include <hip/hip_runtime.h>
#include <math.h>

#define LOG2E 1.44269504088896340736f
#define LN2   0.69314718055994530942f

typedef _Float16 half8 __attribute__((ext_vector_type(8)));
typedef float f32x4v __attribute__((ext_vector_type(4)));

#define TROW 24   // halves per LDS T-row (48B): 16B-aligned b128, <=2-way banks

// ---------------------------------------------------------------------------
// kA (flipped, 2-phase): wave owns 64 f-rows (4 invariant A-frags, [Ah|Al]
// along K); T hi/lo staged 128 g at a time (LDS 16.4 KB -> 9 blocks/CU cap;
// VGPR 64 -> 8; grid 2048 = 8/CU fully resident, 32 waves/CU).
//   MFMA1: A1 x [Th|Th] ; MFMA2: A1 x [Tl|0]   (drops only Al·Tl ~ 2^-22)
// grid (8 gs, 8 fb, 32 b), block 256.
// ---------------------------------------------------------------------------
template <bool ATOMIC>
__global__ __launch_bounds__(256, 4) void kA(const float* __restrict__ data,
                                             const float* __restrict__ attn,
                                             float* __restrict__ Lout) {
    __shared__ _Float16 ThL[128 * TROW];  // 6 KB
    __shared__ _Float16 TlL[128 * TROW];  // 6 KB
    __shared__ _Float16 zeroH[8];
    __shared__ float Lw[4][256];          // 4 KB
    const int tid = threadIdx.x;
    const int b = blockIdx.z, fb = blockIdx.y, gs = blockIdx.x;
    const int wave = tid >> 6, lane = tid & 63;
    const int n = lane & 15, q = lane >> 4;
    const int g0 = gs * 256;

    if (tid < 8) zeroH[tid] = (_Float16)0.0f;

    // ---- Invariant A-fragments: [Ah|Al] along K (q<2: hi, q>=2: lo) ----
    half8 A1[4];
    {
        const float* Ab = data + (size_t)b * 16 * 2048;
        const int frow = fb * 256 + wave * 64;
#pragma unroll
        for (int r = 0; r < 4; ++r) {
            half8 a;
#pragma unroll
            for (int j = 0; j < 8; ++j) {
                const int s = (q & 1) * 8 + j;
                float x = Ab[(size_t)s * 2048 + frow + r * 16 + n];
                _Float16 h = (_Float16)x;
                a[j] = (q < 2) ? h : (_Float16)(x - (float)h);
            }
            A1[r] = a;
        }
    }

    // B1: all lanes read ThL at s=(q&1)*8+j.  B2: q<2 read TlL at s=q*8+j,
    // q>=2 read the shared zero fragment (wave-broadcast, free).
    const _Float16* b1base = ThL + (q & 1) * 8;
    const _Float16* b2base = (q < 2) ? (TlL + q * 8) : zeroH;
    const int b2stride = (q < 2) ? TROW : 0;

    const float* Tb = attn + (size_t)b * 16 * 2048 + g0;
    const int gl = tid >> 1;        // 0..127: local g row this thread stages
    const int sh = (tid & 1) * 8;   // s-half

    for (int p = 0; p < 2; ++p) {
        // ---- Stage 128 g of T hi/lo (pre-scaled by log2e), [g][s] layout ----
        {
            const int g = p * 128 + gl;
            half8 hv, lv;
#pragma unroll
            for (int j = 0; j < 8; ++j) {
                float x = Tb[(size_t)(sh + j) * 2048 + g] * LOG2E;
                _Float16 h = (_Float16)x;
                hv[j] = h;
                lv[j] = (_Float16)(x - (float)h);
            }
            *(half8*)(ThL + gl * TROW + sh) = hv;
            *(half8*)(TlL + gl * TROW + sh) = lv;
        }
        __syncthreads();

        for (int gt = 0; gt < 8; ++gt) {
            const int gp = gt * 16 + n;   // local g (0..127)
            half8 B1 = *(const half8*)(b1base + gp * TROW);
            half8 B2 = *(const half8*)(b2base + gp * b2stride);
            float s0 = 0.f, s1 = 0.f;     // two chains: halve serial add depth
#pragma unroll
            for (int r = 0; r < 4; ++r) {
                f32x4v C = {0.f, 0.f, 0.f, 0.f};
                C = __builtin_amdgcn_mfma_f32_16x16x32_f16(A1[r], B1, C, 0, 0, 0);
                C = __builtin_amdgcn_mfma_f32_16x16x32_f16(A1[r], B2, C, 0, 0, 0);
                float e = __builtin_amdgcn_exp2f(C[0]) + __builtin_amdgcn_exp2f(C[1])
                        + __builtin_amdgcn_exp2f(C[2]) + __builtin_amdgcn_exp2f(C[3]);
                if (r & 1) s1 += e; else s0 += e;
            }
            float sum = s0 + s1;
            sum += __shfl_xor(sum, 16);
            sum += __shfl_xor(sum, 32);
            if (q == 0) Lw[wave][p * 128 + gp] = sum;
        }
        __syncthreads();  // protect ThL/TlL before next-phase staging
    }

    {
        const float v = Lw[0][tid] + Lw[1][tid] + Lw[2][tid] + Lw[3][tid];
        if (ATOMIC)
            atomicAdd(&Lout[(size_t)b * 2048 + g0 + tid], v);
        else
            Lout[((size_t)fb * 32 + b) * 2048 + g0 + tid] = v;
    }
}

// ---------------------------------------------------------------------------
// kTail: per (256-g segment, b): L = ln2*log2(sum Lpart), c-partials, M-partials.
// grid (8, 32), block 256.
// ---------------------------------------------------------------------------
#define TP 260
__global__ __launch_bounds__(256) void kTail(const float* __restrict__ attn,
                                             const float* __restrict__ Lpart, int nparts,
                                             float* __restrict__ Mpart,
                                             float* __restrict__ cpart) {
    __shared__ float Tsh[16 * TP];   // 16.6 KB
    __shared__ float Lsh[256];
    __shared__ float red[16][17];
    const int tid = threadIdx.x;
    const int seg = blockIdx.x, b = blockIdx.y;
    const int g0 = seg * 256;

#pragma unroll
    for (int s = 0; s < 16; ++s)
        Tsh[s * TP + tid] = attn[(size_t)(b * 16 + s) * 2048 + g0 + tid];
    {
        float sum = 0.f;
        for (int p = 0; p < nparts; ++p)
            sum += Lpart[((size_t)p * 32 + b) * 2048 + g0 + tid];
        Lsh[tid] = LN2 * __builtin_amdgcn_logf(sum);
    }
    __syncthreads();

    // c-partial: t = tid&15 over a 16-g subrange
    {
        const int t = tid & 15, i = tid >> 4;
        float acc = 0.f;
#pragma unroll
        for (int k = 0; k < 4; ++k) {
            float4 l  = *(const float4*)(Lsh + i * 16 + k * 4);
            float4 tv = *(const float4*)(Tsh + t * TP + i * 16 + k * 4);
            acc += l.x * tv.x + l.y * tv.y + l.z * tv.z + l.w * tv.w;
        }
        red[t][i] = acc;
    }
    __syncthreads();
    if (tid < 16) {
        float s = 0.f;
#pragma unroll
        for (int k = 0; k < 16; ++k) s += red[tid][k];
        cpart[((size_t)seg * 32 + b) * 16 + tid] = s;
    }

    // M-partial: thread = (s,t)
    {
        const int s = tid >> 4, t = tid & 15;
        float a0 = 0.f, a1 = 0.f;
#pragma unroll 4
        for (int qk = 0; qk < 32; ++qk) {
            float4 x = *(const float4*)(Tsh + s * TP + qk * 8);
            float4 y = *(const float4*)(Tsh + t * TP + qk * 8);
            a0 += x.x * y.x + x.y * y.y + x.z * y.z + x.w * y.w;
            float4 x2 = *(const float4*)(Tsh + s * TP + qk * 8 + 4);
            float4 y2 = *(const float4*)(Tsh + t * TP + qk * 8 + 4);
            a1 += x2.x * y2.x + x2.y * y2.y + x2.z * y2.z + x2.w * y2.w;
        }
        Mpart[((size_t)seg * 32 + b) * 256 + tid] = a0 + a1;
    }
}

// ---------------------------------------------------------------------------
// kC2: fold M/c partials with W,bias (redundant per block, cheap) + epilogue.
// grid (8, 32), block 256.
// ---------------------------------------------------------------------------
__global__ __launch_bounds__(256) void kC2(const float* __restrict__ data,
                                           const float* __restrict__ Mpart,
                                           const float* __restrict__ cpart,
                                           const float* __restrict__ W,
                                           const float* __restrict__ bias,
                                           float* __restrict__ out) {
    __shared__ float Msh[256];
    __shared__ float csh[16];
    __shared__ float Vsh[256];
    __shared__ float w0sh[16];
    const int tid = threadIdx.x;
    const int b = blockIdx.y;
    const int f = blockIdx.x * 256 + tid;

    {
        float m = 0.f;
#pragma unroll
        for (int p = 0; p < 8; ++p) m += Mpart[((size_t)p * 32 + b) * 256 + tid];
        Msh[tid] = m;
        if (tid < 16) {
            float c = 0.f;
#pragma unroll
            for (int p = 0; p < 8; ++p) c += cpart[((size_t)p * 32 + b) * 16 + tid];
            csh[tid] = c;
        }
    }
    __syncthreads();
    {
        const int s = tid >> 4, j = tid & 15;
        float acc = 0.f;
#pragma unroll
        for (int t = 0; t < 16; ++t) acc += Msh[s * 16 + t] * W[j * 32 + t];
        Vsh[s * 16 + j] = acc + W[j * 32 + 16 + s];
        if (s == 0) {
            float w0 = 0.f;
#pragma unroll
            for (int t = 0; t < 16; ++t) w0 += csh[t] * W[j * 32 + t];
            w0sh[j] = bias[j] - w0;
        }
    }
    __syncthreads();

    float As[16];
#pragma unroll
    for (int s = 0; s < 16; ++s)
        As[s] = data[(size_t)(b * 16 + s) * 2048 + f];
#pragma unroll
    for (int j = 0; j < 16; ++j) {
        float p = w0sh[j];
#pragma unroll
        for (int s = 0; s < 16; ++s) p += As[s] * Vsh[s * 16 + j];
        float e = __builtin_amdgcn_exp2f(-LOG2E * p);
        float gate = __builtin_amdgcn_rcpf(1.0f + e);
        size_t r = (size_t)(j * 32 + b) * 2048 + f;
        out[r] = gate * data[r];
    }
}

extern "C" void kernel_launch(void* const* d_in, const int* in_sizes, int n_in,
                              void* d_out, int out_size, void* d_ws, size_t ws_size,
                              hipStream_t stream) {
    const float* data = (const float*)d_in[0];
    const float* attn = (const float*)d_in[1];
    const float* W    = (const float*)d_in[2];
    const float* bias = (const float*)d_in[3];
    float* out = (float*)d_out;
    float* ws  = (float*)d_ws;

    // big layout: Lpart[8][32][2048] | Mpart[8][32][256] | cpart[8][32][16]
    const size_t LP = 8 * 32 * 2048;              // 524288
    const size_t need_big = LP + 65536 + 4096;

    if (ws_size >= need_big * sizeof(float)) {
        float* Lpart = ws;
        float* Mpart = ws + LP;
        float* cpart = Mpart + 65536;
        kA<false><<<dim3(8, 8, 32), 256, 0, stream>>>(data, attn, Lpart);
        kTail<<<dim3(8, 32), 256, 0, stream>>>(attn, Lpart, 8, Mpart, cpart);
        kC2<<<dim3(8, 32), 256, 0, stream>>>(data, Mpart, cpart, W, bias, out);
    } else {
        float* Lsum  = ws;            // 65536
        float* Mpart = ws + 65536;
        float* cpart = Mpart + 65536;
        hipMemsetAsync(Lsum, 0, 65536 * sizeof(float), stream);
        kA<true><<<dim3(8, 8, 32), 256, 0, stream>>>(data, attn, Lsum);
        kTail<<<dim3(8, 32), 256, 0, stream>>>(attn, Lsum, 1, Mpart, cpart);
        kC2<<<dim3(8, 32), 256, 0, stream>>>(data, Mpart, cpart, W, bias, out);
    }
}

// Round 8
// 97.948 us; speedup vs baseline: 1.0102x; 1.0102x over previous
//
#include <hip/hip_runtime.h>
#include <math.h>

#define LOG2E 1.44269504088896340736f
#define LN2   0.69314718055994530942f

typedef _Float16 half8 __attribute__((ext_vector_type(8)));
typedef float f32x4v __attribute__((ext_vector_type(4)));

#define TROW 24   // halves per LDS T-row (48B): 16B-aligned b128, <=2-way banks

// ---------------------------------------------------------------------------
// kA (flipped, 2-phase, 2-tile ILP): wave owns 64 f-rows (4 invariant A-frags,
// [Ah|Al] along K); T hi/lo staged 128 g at a time. Inner loop processes TWO
// 16-g tiles per iteration: 4 ds_read_b128 issued together (4 outstanding),
// 16 independent MFMAs, 32 exp2s, then both shuffle-reduces — doubles the
// independent work between s_waitcnt stalls vs r7.
//   MFMA1: A1 x [Th|Th] ; MFMA2: A1 x [Tl|0]   (drops only Al·Tl ~ 2^-22)
// grid (8 gs, 8 fb, 32 b), block 256.
// ---------------------------------------------------------------------------
template <bool ATOMIC>
__global__ __launch_bounds__(256, 4) void kA(const float* __restrict__ data,
                                             const float* __restrict__ attn,
                                             float* __restrict__ Lout) {
    __shared__ _Float16 ThL[128 * TROW];  // 6 KB
    __shared__ _Float16 TlL[128 * TROW];  // 6 KB
    __shared__ _Float16 zeroH[8];
    __shared__ float Lw[4][256];          // 4 KB
    const int tid = threadIdx.x;
    const int b = blockIdx.z, fb = blockIdx.y, gs = blockIdx.x;
    const int wave = tid >> 6, lane = tid & 63;
    const int n = lane & 15, q = lane >> 4;
    const int g0 = gs * 256;

    if (tid < 8) zeroH[tid] = (_Float16)0.0f;

    // ---- Invariant A-fragments: [Ah|Al] along K (q<2: hi, q>=2: lo) ----
    half8 A1[4];
    {
        const float* Ab = data + (size_t)b * 16 * 2048;
        const int frow = fb * 256 + wave * 64;
#pragma unroll
        for (int r = 0; r < 4; ++r) {
            half8 a;
#pragma unroll
            for (int j = 0; j < 8; ++j) {
                const int s = (q & 1) * 8 + j;
                float x = Ab[(size_t)s * 2048 + frow + r * 16 + n];
                _Float16 h = (_Float16)x;
                a[j] = (q < 2) ? h : (_Float16)(x - (float)h);
            }
            A1[r] = a;
        }
    }

    // B1: all lanes read ThL at s=(q&1)*8+j.  B2: q<2 read TlL at s=q*8+j,
    // q>=2 read the shared zero fragment (wave-broadcast).
    const _Float16* b1base = ThL + (q & 1) * 8;
    const _Float16* b2base = (q < 2) ? (TlL + q * 8) : zeroH;
    const int b2stride = (q < 2) ? TROW : 0;

    const float* Tb = attn + (size_t)b * 16 * 2048 + g0;
    const int gl = tid >> 1;        // 0..127: local g row this thread stages
    const int sh = (tid & 1) * 8;   // s-half

    for (int p = 0; p < 2; ++p) {
        // ---- Stage 128 g of T hi/lo (pre-scaled by log2e), [g][s] layout ----
        {
            const int g = p * 128 + gl;
            half8 hv, lv;
#pragma unroll
            for (int j = 0; j < 8; ++j) {
                float x = Tb[(size_t)(sh + j) * 2048 + g] * LOG2E;
                _Float16 h = (_Float16)x;
                hv[j] = h;
                lv[j] = (_Float16)(x - (float)h);
            }
            *(half8*)(ThL + gl * TROW + sh) = hv;
            *(half8*)(TlL + gl * TROW + sh) = lv;
        }
        __syncthreads();

#pragma unroll
        for (int gg = 0; gg < 4; ++gg) {
            const int gpA = gg * 32 + n;        // tile 2gg
            const int gpB = gg * 32 + 16 + n;   // tile 2gg+1
            // 4 LDS reads issued together -> 4 outstanding lgkm
            half8 B1a = *(const half8*)(b1base + gpA * TROW);
            half8 B2a = *(const half8*)(b2base + gpA * b2stride);
            half8 B1b = *(const half8*)(b1base + gpB * TROW);
            half8 B2b = *(const half8*)(b2base + gpB * b2stride);

            // 16 independent MFMAs (8 per tile), interleaved a/b
            f32x4v Ca[4], Cb[4];
#pragma unroll
            for (int r = 0; r < 4; ++r) {
                f32x4v ta = {0.f, 0.f, 0.f, 0.f};
                ta = __builtin_amdgcn_mfma_f32_16x16x32_f16(A1[r], B1a, ta, 0, 0, 0);
                f32x4v tb = {0.f, 0.f, 0.f, 0.f};
                tb = __builtin_amdgcn_mfma_f32_16x16x32_f16(A1[r], B1b, tb, 0, 0, 0);
                ta = __builtin_amdgcn_mfma_f32_16x16x32_f16(A1[r], B2a, ta, 0, 0, 0);
                tb = __builtin_amdgcn_mfma_f32_16x16x32_f16(A1[r], B2b, tb, 0, 0, 0);
                Ca[r] = ta;
                Cb[r] = tb;
            }

            // 32 exp2s in two independent accumulation chains per tile
            float sa0 = 0.f, sa1 = 0.f, sb0 = 0.f, sb1 = 0.f;
#pragma unroll
            for (int r = 0; r < 4; ++r) {
                float ea = __builtin_amdgcn_exp2f(Ca[r][0]) + __builtin_amdgcn_exp2f(Ca[r][1])
                         + __builtin_amdgcn_exp2f(Ca[r][2]) + __builtin_amdgcn_exp2f(Ca[r][3]);
                float eb = __builtin_amdgcn_exp2f(Cb[r][0]) + __builtin_amdgcn_exp2f(Cb[r][1])
                         + __builtin_amdgcn_exp2f(Cb[r][2]) + __builtin_amdgcn_exp2f(Cb[r][3]);
                if (r & 1) { sa1 += ea; sb1 += eb; } else { sa0 += ea; sb0 += eb; }
            }
            float sa = sa0 + sa1, sb = sb0 + sb1;
            // both shuffle-reduces back-to-back (independent chains)
            sa += __shfl_xor(sa, 16);
            sb += __shfl_xor(sb, 16);
            sa += __shfl_xor(sa, 32);
            sb += __shfl_xor(sb, 32);
            if (q == 0) {
                Lw[wave][p * 128 + gpA] = sa;
                Lw[wave][p * 128 + gpB] = sb;
            }
        }
        __syncthreads();  // protect ThL/TlL before next-phase staging
    }

    {
        const float v = Lw[0][tid] + Lw[1][tid] + Lw[2][tid] + Lw[3][tid];
        if (ATOMIC)
            atomicAdd(&Lout[(size_t)b * 2048 + g0 + tid], v);
        else
            Lout[((size_t)fb * 32 + b) * 2048 + g0 + tid] = v;
    }
}

// ---------------------------------------------------------------------------
// kTail: per (256-g segment, b): L = ln2*log2(sum Lpart), c-partials, M-partials.
// grid (8, 32), block 256.
// ---------------------------------------------------------------------------
#define TP 260
__global__ __launch_bounds__(256) void kTail(const float* __restrict__ attn,
                                             const float* __restrict__ Lpart, int nparts,
                                             float* __restrict__ Mpart,
                                             float* __restrict__ cpart) {
    __shared__ float Tsh[16 * TP];   // 16.6 KB
    __shared__ float Lsh[256];
    __shared__ float red[16][17];
    const int tid = threadIdx.x;
    const int seg = blockIdx.x, b = blockIdx.y;
    const int g0 = seg * 256;

#pragma unroll
    for (int s = 0; s < 16; ++s)
        Tsh[s * TP + tid] = attn[(size_t)(b * 16 + s) * 2048 + g0 + tid];
    {
        float sum = 0.f;
        for (int p = 0; p < nparts; ++p)
            sum += Lpart[((size_t)p * 32 + b) * 2048 + g0 + tid];
        Lsh[tid] = LN2 * __builtin_amdgcn_logf(sum);
    }
    __syncthreads();

    // c-partial: t = tid&15 over a 16-g subrange
    {
        const int t = tid & 15, i = tid >> 4;
        float acc = 0.f;
#pragma unroll
        for (int k = 0; k < 4; ++k) {
            float4 l  = *(const float4*)(Lsh + i * 16 + k * 4);
            float4 tv = *(const float4*)(Tsh + t * TP + i * 16 + k * 4);
            acc += l.x * tv.x + l.y * tv.y + l.z * tv.z + l.w * tv.w;
        }
        red[t][i] = acc;
    }
    __syncthreads();
    if (tid < 16) {
        float s = 0.f;
#pragma unroll
        for (int k = 0; k < 16; ++k) s += red[tid][k];
        cpart[((size_t)seg * 32 + b) * 16 + tid] = s;
    }

    // M-partial: thread = (s,t)
    {
        const int s = tid >> 4, t = tid & 15;
        float a0 = 0.f, a1 = 0.f;
#pragma unroll 4
        for (int qk = 0; qk < 32; ++qk) {
            float4 x = *(const float4*)(Tsh + s * TP + qk * 8);
            float4 y = *(const float4*)(Tsh + t * TP + qk * 8);
            a0 += x.x * y.x + x.y * y.y + x.z * y.z + x.w * y.w;
            float4 x2 = *(const float4*)(Tsh + s * TP + qk * 8 + 4);
            float4 y2 = *(const float4*)(Tsh + t * TP + qk * 8 + 4);
            a1 += x2.x * y2.x + x2.y * y2.y + x2.z * y2.z + x2.w * y2.w;
        }
        Mpart[((size_t)seg * 32 + b) * 256 + tid] = a0 + a1;
    }
}

// ---------------------------------------------------------------------------
// kC2: fold M/c partials with W,bias (redundant per block, cheap) + epilogue.
// grid (8, 32), block 256.
// ---------------------------------------------------------------------------
__global__ __launch_bounds__(256) void kC2(const float* __restrict__ data,
                                           const float* __restrict__ Mpart,
                                           const float* __restrict__ cpart,
                                           const float* __restrict__ W,
                                           const float* __restrict__ bias,
                                           float* __restrict__ out) {
    __shared__ float Msh[256];
    __shared__ float csh[16];
    __shared__ float Vsh[256];
    __shared__ float w0sh[16];
    const int tid = threadIdx.x;
    const int b = blockIdx.y;
    const int f = blockIdx.x * 256 + tid;

    {
        float m = 0.f;
#pragma unroll
        for (int p = 0; p < 8; ++p) m += Mpart[((size_t)p * 32 + b) * 256 + tid];
        Msh[tid] = m;
        if (tid < 16) {
            float c = 0.f;
#pragma unroll
            for (int p = 0; p < 8; ++p) c += cpart[((size_t)p * 32 + b) * 16 + tid];
            csh[tid] = c;
        }
    }
    __syncthreads();
    {
        const int s = tid >> 4, j = tid & 15;
        float acc = 0.f;
#pragma unroll
        for (int t = 0; t < 16; ++t) acc += Msh[s * 16 + t] * W[j * 32 + t];
        Vsh[s * 16 + j] = acc + W[j * 32 + 16 + s];
        if (s == 0) {
            float w0 = 0.f;
#pragma unroll
            for (int t = 0; t < 16; ++t) w0 += csh[t] * W[j * 32 + t];
            w0sh[j] = bias[j] - w0;
        }
    }
    __syncthreads();

    float As[16];
#pragma unroll
    for (int s = 0; s < 16; ++s)
        As[s] = data[(size_t)(b * 16 + s) * 2048 + f];
#pragma unroll
    for (int j = 0; j < 16; ++j) {
        float p = w0sh[j];
#pragma unroll
        for (int s = 0; s < 16; ++s) p += As[s] * Vsh[s * 16 + j];
        float e = __builtin_amdgcn_exp2f(-LOG2E * p);
        float gate = __builtin_amdgcn_rcpf(1.0f + e);
        size_t r = (size_t)(j * 32 + b) * 2048 + f;
        out[r] = gate * data[r];
    }
}

extern "C" void kernel_launch(void* const* d_in, const int* in_sizes, int n_in,
                              void* d_out, int out_size, void* d_ws, size_t ws_size,
                              hipStream_t stream) {
    const float* data = (const float*)d_in[0];
    const float* attn = (const float*)d_in[1];
    const float* W    = (const float*)d_in[2];
    const float* bias = (const float*)d_in[3];
    float* out = (float*)d_out;
    float* ws  = (float*)d_ws;

    // big layout: Lpart[8][32][2048] | Mpart[8][32][256] | cpart[8][32][16]
    const size_t LP = 8 * 32 * 2048;              // 524288
    const size_t need_big = LP + 65536 + 4096;

    if (ws_size >= need_big * sizeof(float)) {
        float* Lpart = ws;
        float* Mpart = ws + LP;
        float* cpart = Mpart + 65536;
        kA<false><<<dim3(8, 8, 32), 256, 0, stream>>>(data, attn, Lpart);
        kTail<<<dim3(8, 32), 256, 0, stream>>>(attn, Lpart, 8, Mpart, cpart);
        kC2<<<dim3(8, 32), 256, 0, stream>>>(data, Mpart, cpart, W, bias, out);
    } else {
        float* Lsum  = ws;            // 65536
        float* Mpart = ws + 65536;
        float* cpart = Mpart + 65536;
        hipMemsetAsync(Lsum, 0, 65536 * sizeof(float), stream);
        kA<true><<<dim3(8, 8, 32), 256, 0, stream>>>(data, attn, Lsum);
        kTail<<<dim3(8, 32), 256, 0, stream>>>(attn, Lsum, 1, Mpart, cpart);
        kC2<<<dim3(8, 32), 256, 0, stream>>>(data, Mpart, cpart, W, bias, out);
    }
}